// Round 17
// baseline (88.068 us; speedup 1.0000x reference)
//
#include <hip/hip_runtime.h>
#include <hip/hip_bf16.h>

typedef __attribute__((ext_vector_type(8))) __bf16 bf16x8;
typedef __attribute__((ext_vector_type(4))) float f32x4;
typedef __attribute__((ext_vector_type(4))) unsigned int u32x4;
typedef unsigned long long ull;

#define NB 16
#define CIN 32
#define COUT 64
#define HW 224
#define HWHW (HW * HW)          // 50176
#define CHW (CIN * HW * HW)     // 1605632
#define WROW 296                // padded LDS row pitch in shorts (148 dwords)

__device__ __forceinline__ unsigned short f2bf(float f) {
    __hip_bfloat16 h = __float2bfloat16(f);
    return __builtin_bit_cast(unsigned short, h);
}

// ---- K1: weight OIHW fp32 -> wT[co][tap][cin] bf16 (64*9*32 = 18432) ----
__global__ void k_wxform(const float* __restrict__ w, unsigned short* __restrict__ wT) {
    int i = blockIdx.x * 256 + threadIdx.x;
    if (i >= COUT * 9 * CIN) return;
    int co = i / (9 * CIN);
    int r  = i % (9 * CIN);
    int tap = r / CIN;
    int c   = r % CIN;
    wT[i] = f2bf(w[(co * CIN + c) * 9 + tap]);
}

// ---- K2: fused conv, 8 waves x 32px x 64cout (512-thread block).
// r16 base (wT in LDS, wide bursts, bpermute dedup, nt stores) with the
// occupancy constraint finally solved: acc 64->32 regs, raw 48->32, waves
// still split PX (no gather duplication, r13 lesson), (512,4) gives a
// clean 128-reg cap (r15's (448,4) strangled VGPR to 56). 2 blocks/CU =
// 50% occupancy vs 26.6%. Wave 7 (px 224-255) fully masked = 12.5% MFMA
// waste, accepted (r14 carried the same and won). ----
__global__ __launch_bounds__(512, 4)
void k_fused(const float* __restrict__ x, const unsigned short* __restrict__ wT,
             const float* __restrict__ bias, float* __restrict__ out) {
    __shared__ __align__(16) unsigned short wlds[COUT * WROW];   // 37888 B

    int bid = blockIdx.x;
    int wg  = (bid & 7) * 448 + (bid >> 3);   // XCD-chunked swizzle, 3584 = 8*448
    int b = wg / HW, h = wg % HW;
    int tid = threadIdx.x;

    // stage wT -> LDS (row remap 288 -> 296 shorts), once per block
    {
        const u32x4* src = reinterpret_cast<const u32x4*>(wT);
        u32x4* dst = reinterpret_cast<u32x4*>(wlds);
        #pragma unroll
        for (int k = 0; k < 5; ++k) {              // 2304 x4dwords, 512 thr
            int i = k * 512 + tid;
            if (i < 2304) {
                int co = i / 36, t = i % 36;
                dst[co * 37 + t] = src[i];
            }
        }
    }
    __syncthreads();

    int wave = tid >> 6, lane = tid & 63;
    int r = lane & 15;                // px-local / cout-local row idx
    int q = lane >> 4;
    int chunk = q * 8;                // cin sub-chunk
    int px0 = wave * 32;              // wave 7: 224 (fully masked)
    const float* xb = x + (ull)b * CHW + (ull)chunk * HWHW;

    // byte-index regs for ds_bpermute rotations within each 16-lane group
    int idxm = (((lane & 48) | ((lane - 1) & 15)) << 2);   // pull from r-1 (wrap)
    int idxp = (((lane & 48) | ((lane + 1) & 15)) << 2);   // pull from r+1 (wrap)
    bool r0  = (r == 0), r15 = (r == 15);

    // center/halo coords + validity (clamped, branch-free)
    int pc[2];
    unsigned int cm[2];
    #pragma unroll
    for (int pf = 0; pf < 2; ++pf) {
        int cpx = px0 + pf * 16 + r;
        cm[pf] = (cpx < HW) ? 0xFFFFFFFFu : 0u;
        pc[pf] = (cpx < HW) ? cpx : HW - 1;
    }
    int hlp = px0 - 1;
    unsigned int lmask = (hlp >= 0) ? 0xFFFFFFFFu : 0u;
    hlp = (hlp >= 0) ? hlp : 0;
    int hrp = px0 + 32;
    unsigned int rmask = (hrp < HW) ? 0xFFFFFFFFu : 0u;
    hrp = (hrp < HW) ? hrp : HW - 1;

    f32x4 acc[4][2];                  // [cout frag][px frag] = 32 regs
    #pragma unroll
    for (int i = 0; i < 4; ++i) {
        acc[i][0] = (f32x4){0.f, 0.f, 0.f, 0.f};
        acc[i][1] = (f32x4){0.f, 0.f, 0.f, 0.f};
    }

    #pragma unroll
    for (int dh = 0; dh < 3; ++dh) {
        int hy = h + dh - 1;
        unsigned int rowm = ((unsigned)hy < (unsigned)HW) ? 0xFFFFFFFFu : 0u;
        int hyc = hy < 0 ? 0 : (hy > HW - 1 ? HW - 1 : hy);
        const float* xrow = xb + (ull)hyc * HW;

        // ---- phase A: issue all 32 loads of this dh before any use ----
        float raw[32];
        #pragma unroll
        for (int pf = 0; pf < 2; ++pf) {
            const float* p = xrow + pc[pf];
            #pragma unroll
            for (int j = 0; j < 8; ++j)
                raw[pf * 8 + j] = p[(ull)j * HWHW];
        }
        {
            const float* p = xrow + hlp;
            #pragma unroll
            for (int j = 0; j < 8; ++j) raw[16 + j] = p[(ull)j * HWHW];
        }
        {
            const float* p = xrow + hrp;
            #pragma unroll
            for (int j = 0; j < 8; ++j) raw[24 + j] = p[(ull)j * HWHW];
        }
        __builtin_amdgcn_sched_barrier(0);   // keep all loads above the packs

        // ---- phase B: pack to bf16 pairs + masks ----
        unsigned int own[2][4], hl[4], hr[4];
        #pragma unroll
        for (int pf = 0; pf < 2; ++pf) {
            unsigned int zm = cm[pf] & rowm;
            #pragma unroll
            for (int j = 0; j < 4; ++j)
                own[pf][j] = ((unsigned)f2bf(raw[pf * 8 + 2 * j]) |
                              ((unsigned)f2bf(raw[pf * 8 + 2 * j + 1]) << 16)) & zm;
        }
        {
            unsigned int zm = lmask & rowm;
            #pragma unroll
            for (int j = 0; j < 4; ++j)
                hl[j] = ((unsigned)f2bf(raw[16 + 2 * j]) |
                         ((unsigned)f2bf(raw[16 + 2 * j + 1]) << 16)) & zm;
        }
        {
            unsigned int zm = rmask & rowm;
            #pragma unroll
            for (int j = 0; j < 4; ++j)
                hr[j] = ((unsigned)f2bf(raw[24 + 2 * j]) |
                         ((unsigned)f2bf(raw[24 + 2 * j + 1]) << 16)) & zm;
        }

        // ---- phase W: hoist this dh's 12 wf fragments from LDS ----
        bf16x8 wfd[3][4];
        #pragma unroll
        for (int dw = 0; dw < 3; ++dw)
            #pragma unroll
            for (int cf = 0; cf < 4; ++cf)
                wfd[dw][cf] = *reinterpret_cast<const bf16x8*>(
                    wlds + (cf * 16 + r) * WROW + (dh * 3 + dw) * 32 + chunk);

        // ---- phase C: shifts via bpermute + MFMA ----
        #pragma unroll
        for (int dw = 0; dw < 3; ++dw) {
            bf16x8 xf[2];
            if (dw == 1) {
                xf[0] = __builtin_bit_cast(bf16x8,
                        (u32x4){own[0][0], own[0][1], own[0][2], own[0][3]});
                xf[1] = __builtin_bit_cast(bf16x8,
                        (u32x4){own[1][0], own[1][1], own[1][2], own[1][3]});
            } else if (dw == 0) {        // col px-1: pull from r-1
                u32x4 t0, t1;
                #pragma unroll
                for (int j = 0; j < 4; ++j) {
                    int A0 = __builtin_amdgcn_ds_bpermute(idxm, (int)own[0][j]);
                    int A1 = __builtin_amdgcn_ds_bpermute(idxm, (int)own[1][j]);
                    t0[j] = (unsigned int)(r0 ? (int)hl[j] : A0);
                    t1[j] = (unsigned int)(r0 ? A0 : A1);   // r0 wraps to own[0][15]
                }
                xf[0] = __builtin_bit_cast(bf16x8, t0);
                xf[1] = __builtin_bit_cast(bf16x8, t1);
            } else {                      // col px+1: pull from r+1
                u32x4 t0, t1;
                #pragma unroll
                for (int j = 0; j < 4; ++j) {
                    int B0 = __builtin_amdgcn_ds_bpermute(idxp, (int)own[0][j]);
                    int B1 = __builtin_amdgcn_ds_bpermute(idxp, (int)own[1][j]);
                    t0[j] = (unsigned int)(r15 ? B1 : B0);  // r15 wraps to own[1][0]
                    t1[j] = (unsigned int)(r15 ? (int)hr[j] : B1);
                }
                xf[0] = __builtin_bit_cast(bf16x8, t0);
                xf[1] = __builtin_bit_cast(bf16x8, t1);
            }
            #pragma unroll
            for (int cf = 0; cf < 4; ++cf) {
                acc[cf][0] = __builtin_amdgcn_mfma_f32_16x16x32_bf16(xf[0], wfd[dw][cf], acc[cf][0], 0, 0, 0);
                acc[cf][1] = __builtin_amdgcn_mfma_f32_16x16x32_bf16(xf[1], wfd[dw][cf], acc[cf][1], 0, 0, 0);
            }
        }
    }

    // epilogue: D row = px = q*4+reg, col = cout = r; nt f32x4 stores
    #pragma unroll
    for (int cf = 0; cf < 4; ++cf) {
        int co = cf * 16 + r;
        float bv = bias[co];
        float* orow = out + ((ull)(b * COUT + co) * HW + h) * HW;
        #pragma unroll
        for (int pf = 0; pf < 2; ++pf) {
            int pxb = px0 + pf * 16;
            if (pxb < HW) {                  // wave 7 / tail frags masked
                int px = pxb + q * 4;
                f32x4 v = acc[cf][pf] + bv;
                __builtin_nontemporal_store(v, reinterpret_cast<f32x4*>(orow + px));
            }
        }
    }
}

// ---- fallback: naive direct fp32 conv (used only if ws too small) ----
__global__ void k_naive(const float* __restrict__ x, const float* __restrict__ w,
                        const float* __restrict__ bias, float* __restrict__ out, long long n) {
    long long i = (long long)blockIdx.x * 256 + threadIdx.x;
    if (i >= n) return;
    int wc = i % HW; long long t = i / HW;
    int h = t % HW; t /= HW;
    int co = t % COUT; int b = (int)(t / COUT);
    float s = bias[co];
    for (int c = 0; c < CIN; ++c)
        for (int dh = 0; dh < 3; ++dh) {
            int hy = h + dh - 1; if (hy < 0 || hy >= HW) continue;
            for (int dw = 0; dw < 3; ++dw) {
                int wx = wc + dw - 1; if (wx < 0 || wx >= HW) continue;
                s += x[(((long long)b * CIN + c) * HW + hy) * HW + wx] *
                     w[((co * CIN + c) * 3 + dh) * 3 + dw];
            }
        }
    out[i] = s;
}

extern "C" void kernel_launch(void* const* d_in, const int* in_sizes, int n_in,
                              void* d_out, int out_size, void* d_ws, size_t ws_size,
                              hipStream_t stream) {
    const float* x    = (const float*)d_in[0];
    const float* w    = (const float*)d_in[1];
    const float* bias = (const float*)d_in[2];
    float* out = (float*)d_out;

    if (ws_size < (size_t)(COUT * 9 * CIN * 2 + 1024)) {
        long long n = (long long)NB * COUT * HW * HW;
        k_naive<<<(int)((n + 255) / 256), 256, 0, stream>>>(x, w, bias, out, n);
        return;
    }
    unsigned short* wT = (unsigned short*)d_ws;

    k_wxform<<<72, 256, 0, stream>>>(w, wT);
    k_fused<<<NB * HW, 512, 0, stream>>>(x, wT, bias, out);
}